// Round 16
// baseline (319.563 us; speedup 1.0000x reference)
//
#include <hip/hip_runtime.h>

// GraphSAGE 2-layer, N=100000, E=1600000, 128 -> 64 -> 32.
// Round 16: agg1 feature-sliced + XCD-pinned. Round-15 counters: agg1 55us,
// FETCH 96MB, VALUBusy 39% -> gather working set (12.8MB z1) thrashes every
// 4MB XCD L2; traffic served from L3, latency-bound. New: z1 stored
// SLICE-MAJOR (4 slices x 16 feats = 3.2MB contiguous each; transform1 store
// addressing change only). agg1_sliced pins slice s on XCD pair via
// role = blockIdx&7 (slice=role>>1, node-half=role&1): each role's gathers
// hit ONE L2-resident 3.2MB slice. csr/r1 reads + h writes non-temporal so
// streams don't evict the slice (round-13 lesson). agg2, transforms' math,
// CSR build all byte-identical to round 15.

namespace {
constexpr int N = 100000;
constexpr int E = 1600000;
constexpr int NBLK = (N + 255) / 256;           // 391 scan blocks
constexpr int NT16 = N / 16;                    // 6250 node tiles (exact)
constexpr int NCHUNK = 64;                      // 1600 nodes per chunk
constexpr int CHUNK_N = 1600;
constexpr int CAP = 28000;                      // bucket capacity
constexpr int PA_BLOCKS = 256;
constexpr int PER_BLK = E / PA_BLOCKS;          // 6250 edges per block
}

using bf16x8 = __attribute__((ext_vector_type(8))) short;
using f32x4  = __attribute__((ext_vector_type(4))) float;

__device__ __forceinline__ short f2bf(float f) {
    unsigned u = __builtin_bit_cast(unsigned, f);
    u += 0x7FFFu + ((u >> 16) & 1u);            // RNE truncate to bf16
    return (short)(u >> 16);
}

__device__ __forceinline__ bf16x8 load_frag8(const float* __restrict__ p) {
    const float4* p4 = (const float4*)p;
    float4 f0 = p4[0], f1 = p4[1];
    bf16x8 r;
    r[0] = f2bf(f0.x); r[1] = f2bf(f0.y); r[2] = f2bf(f0.z); r[3] = f2bf(f0.w);
    r[4] = f2bf(f1.x); r[5] = f2bf(f1.y); r[6] = f2bf(f1.z); r[7] = f2bf(f1.w);
    return r;
}

// packed bf16 pair -> two floats
__device__ __forceinline__ float pk_lo(unsigned u) {
    return __builtin_bit_cast(float, u << 16);
}
__device__ __forceinline__ float pk_hi(unsigned u) {
    return __builtin_bit_cast(float, u & 0xFFFF0000u);
}

// ---------------- CSR build ----------------

__global__ __launch_bounds__(256) void detect_dtype(const int* __restrict__ raw,
                                                    int* __restrict__ flag,
                                                    int* __restrict__ bcur) {
    if (threadIdx.x < NCHUNK) bcur[threadIdx.x] = 0;
    int any = 0;
#pragma unroll
    for (int k = 0; k < 64; ++k) {
        int i = threadIdx.x + k * 256;          // first 16384 qwords
        any |= raw[2 * i + 1];
    }
    unsigned long long b = __ballot(any != 0);
    __shared__ int acc[4];
    int w = threadIdx.x >> 6;
    if ((threadIdx.x & 63) == 0) acc[w] = (b != 0ULL) ? 1 : 0;
    __syncthreads();
    if (threadIdx.x == 0) *flag = acc[0] | acc[1] | acc[2] | acc[3];
}

__global__ __launch_bounds__(256) void bucket_edges(
        const int* __restrict__ raw, const int* __restrict__ flag,
        int* __restrict__ bcur, int2* __restrict__ bucket) {
    __shared__ int cnt[NCHUNK];
    __shared__ int res[NCHUNK];
    if (threadIdx.x < NCHUNK) cnt[threadIdx.x] = 0;
    __syncthreads();
    const int is32 = *flag;
    const int e0 = blockIdx.x * PER_BLK;
    for (int i = threadIdx.x; i < PER_BLK; i += 256) {
        int e = e0 + i;
        int d = is32 ? raw[E + e] : raw[2 * ((long long)E + e)];
        atomicAdd(&cnt[d / CHUNK_N], 1);
    }
    __syncthreads();
    if (threadIdx.x < NCHUNK) {
        res[threadIdx.x] = atomicAdd(&bcur[threadIdx.x], cnt[threadIdx.x]);
        cnt[threadIdx.x] = 0;
    }
    __syncthreads();
    for (int i = threadIdx.x; i < PER_BLK; i += 256) {
        int e = e0 + i;
        int d, s;
        if (is32) { d = raw[E + e]; s = raw[e]; }
        else      { d = raw[2 * ((long long)E + e)]; s = raw[2 * (long long)e]; }
        int c = d / CHUNK_N;
        int pos = res[c] + atomicAdd(&cnt[c], 1);
        if (pos < CAP) bucket[(size_t)c * CAP + pos] = make_int2(s, d);
    }
}

__global__ __launch_bounds__(1024) void count2(
        const int* __restrict__ bcur, const int2* __restrict__ bucket,
        int* __restrict__ counts) {
    __shared__ int scnt[CHUNK_N];
    const int chunk = blockIdx.x;
    const int lo = chunk * CHUNK_N;
    for (int i = threadIdx.x; i < CHUNK_N; i += 1024) scnt[i] = 0;
    __syncthreads();
    int n = bcur[chunk]; if (n > CAP) n = CAP;
    const int2* b = bucket + (size_t)chunk * CAP;
    for (int i = threadIdx.x; i < n; i += 1024)
        atomicAdd(&scnt[b[i].y - lo], 1);
    __syncthreads();
    const int lim = N - lo;
    for (int i = threadIdx.x; i < CHUNK_N; i += 1024)
        if (i < lim) counts[lo + i] = scnt[i];
}

__global__ __launch_bounds__(256) void scan1(const int* __restrict__ counts,
                                             int* __restrict__ rowstart,
                                             int* __restrict__ bsum) {
    __shared__ int tmp[256];
    int t = threadIdx.x;
    int i = blockIdx.x * 256 + t;
    int v = (i < N) ? counts[i] : 0;
    tmp[t] = v;
    __syncthreads();
#pragma unroll
    for (int off = 1; off < 256; off <<= 1) {
        int a = (t >= off) ? tmp[t - off] : 0;
        __syncthreads();
        tmp[t] += a;
        __syncthreads();
    }
    if (i < N) rowstart[i] = tmp[t] - v;
    if (t == 255) bsum[blockIdx.x] = tmp[255];
}

__global__ __launch_bounds__(512) void scan2(int* __restrict__ bsum) {
    __shared__ int tmp[512];
    int t = threadIdx.x;
    int v = (t < NBLK) ? bsum[t] : 0;
    tmp[t] = v;
    __syncthreads();
#pragma unroll
    for (int off = 1; off < 512; off <<= 1) {
        int a = (t >= off) ? tmp[t - off] : 0;
        __syncthreads();
        tmp[t] += a;
        __syncthreads();
    }
    if (t < NBLK) bsum[t] = tmp[t] - v;
}

__global__ void scan3(int* __restrict__ rowstart, const int* __restrict__ bsum) {
    int i = blockIdx.x * blockDim.x + threadIdx.x;
    if (i < N) rowstart[i] += bsum[i >> 8];
    if (i == 0) rowstart[N] = E;
}

__global__ __launch_bounds__(1024) void fill2(
        const int* __restrict__ bcur, const int2* __restrict__ bucket,
        const int* __restrict__ rowstart, int* __restrict__ csr) {
    __shared__ int scur[CHUNK_N];
    const int chunk = blockIdx.x;
    const int lo = chunk * CHUNK_N;
    const int lim = N - lo;
    for (int i = threadIdx.x; i < CHUNK_N; i += 1024)
        scur[i] = (i < lim) ? rowstart[lo + i] : 0;
    __syncthreads();
    int n = bcur[chunk]; if (n > CAP) n = CAP;
    const int2* b = bucket + (size_t)chunk * CAP;
    for (int i = threadIdx.x; i < n; i += 1024) {
        int2 sd = b[i];
        int pos = atomicAdd(&scur[sd.y - lo], 1);
        csr[pos] = sd.x;
    }
}

// ---------------- layer 1 transform (MFMA): z1 slice-major bf16, r1 f32 ----------------
__global__ __launch_bounds__(256) void transform1_mfma(
        const float* __restrict__ x, const float* __restrict__ W1l,
        const float* __restrict__ W1r, unsigned short* __restrict__ z1b,
        float* __restrict__ r1) {
    const int lane = threadIdx.x & 63;
    const int gw = blockIdx.x * 4 + (threadIdx.x >> 6);
    const int q = gw & 1;
    const int r16 = lane & 15;
    const int kgrp = lane >> 4;

    bf16x8 wf[2][2][4];
#pragma unroll
    for (int m = 0; m < 2; ++m) {
        const float* W = m ? W1r : W1l;
#pragma unroll
        for (int c = 0; c < 2; ++c) {
            const float* pw = W + (size_t)(q * 32 + c * 16 + r16) * 128 + kgrp * 8;
#pragma unroll
            for (int kb = 0; kb < 4; ++kb)
                wf[m][c][kb] = load_frag8(pw + kb * 32);
        }
    }

    const int stride = (gridDim.x * 4) >> 1;
    for (int t = gw >> 1; t < NT16; t += stride) {
        const float* px = x + ((size_t)t * 16 + r16) * 128 + kgrp * 8;
        bf16x8 af[4];
#pragma unroll
        for (int kb = 0; kb < 4; ++kb) af[kb] = load_frag8(px + kb * 32);

        f32x4 a00 = {0.f,0.f,0.f,0.f}, a01 = {0.f,0.f,0.f,0.f};
        f32x4 a10 = {0.f,0.f,0.f,0.f}, a11 = {0.f,0.f,0.f,0.f};
#pragma unroll
        for (int kb = 0; kb < 4; ++kb) {
            a00 = __builtin_amdgcn_mfma_f32_16x16x32_bf16(af[kb], wf[0][0][kb], a00, 0, 0, 0);
            a01 = __builtin_amdgcn_mfma_f32_16x16x32_bf16(af[kb], wf[0][1][kb], a01, 0, 0, 0);
            a10 = __builtin_amdgcn_mfma_f32_16x16x32_bf16(af[kb], wf[1][0][kb], a10, 0, 0, 0);
            a11 = __builtin_amdgcn_mfma_f32_16x16x32_bf16(af[kb], wf[1][1][kb], a11, 0, 0, 0);
        }
#pragma unroll
        for (int i = 0; i < 4; ++i) {
            size_t row = (size_t)t * 16 + kgrp * 4 + i;
            // slice-major: slice s block = s*N*16 ushorts; feat q*32+c*16+r16 -> slice 2q+c
            z1b[(size_t)(2 * q + 0) * (N * 16) + row * 16 + r16] = (unsigned short)f2bf(a00[i]);
            z1b[(size_t)(2 * q + 1) * (N * 16) + row * 16 + r16] = (unsigned short)f2bf(a01[i]);
            r1[row * 64 + q * 32 +  0 + r16] = a10[i];
            r1[row * 64 + q * 32 + 16 + r16] = a11[i];
        }
    }
}

// ---------------- layer 2 transform (MFMA): z2 node-major bf16, r2 f32 ----------------
__global__ __launch_bounds__(256) void transform2_mfma(
        const float* __restrict__ h, const float* __restrict__ W2l,
        const float* __restrict__ W2r, unsigned short* __restrict__ z2b,
        float* __restrict__ r2) {
    const int lane = threadIdx.x & 63;
    const int gw = blockIdx.x * 4 + (threadIdx.x >> 6);
    const int r16 = lane & 15;
    const int kgrp = lane >> 4;

    bf16x8 wf[2][2][2];
#pragma unroll
    for (int m = 0; m < 2; ++m) {
        const float* W = m ? W2r : W2l;
#pragma unroll
        for (int c = 0; c < 2; ++c) {
            const float* pw = W + (size_t)(c * 16 + r16) * 64 + kgrp * 8;
#pragma unroll
            for (int kb = 0; kb < 2; ++kb)
                wf[m][c][kb] = load_frag8(pw + kb * 32);
        }
    }

    for (int t = gw; t < NT16; t += gridDim.x * 4) {
        const float* ph = h + ((size_t)t * 16 + r16) * 64 + kgrp * 8;
        bf16x8 af[2];
        af[0] = load_frag8(ph);
        af[1] = load_frag8(ph + 32);

        f32x4 a00 = {0.f,0.f,0.f,0.f}, a01 = {0.f,0.f,0.f,0.f};
        f32x4 a10 = {0.f,0.f,0.f,0.f}, a11 = {0.f,0.f,0.f,0.f};
#pragma unroll
        for (int kb = 0; kb < 2; ++kb) {
            a00 = __builtin_amdgcn_mfma_f32_16x16x32_bf16(af[kb], wf[0][0][kb], a00, 0, 0, 0);
            a01 = __builtin_amdgcn_mfma_f32_16x16x32_bf16(af[kb], wf[0][1][kb], a01, 0, 0, 0);
            a10 = __builtin_amdgcn_mfma_f32_16x16x32_bf16(af[kb], wf[1][0][kb], a10, 0, 0, 0);
            a11 = __builtin_amdgcn_mfma_f32_16x16x32_bf16(af[kb], wf[1][1][kb], a11, 0, 0, 0);
        }
#pragma unroll
        for (int i = 0; i < 4; ++i) {
            size_t row = (size_t)t * 16 + kgrp * 4 + i;
            z2b[row * 32 +  0 + r16] = (unsigned short)f2bf(a00[i]);
            z2b[row * 32 + 16 + r16] = (unsigned short)f2bf(a01[i]);
            r2[row * 32 +  0 + r16] = a10[i];
            r2[row * 32 + 16 + r16] = a11[i];
        }
    }
}

// ---------------- layer 1 aggregation: feature-sliced, XCD-pinned ----------------
// role = blockIdx&7 -> slice = role>>1 (3.2MB, L2-resident), half = role&1.
// Wave: 8 lanes per row x 8 rows per gather batch; 3 shfl_xor folds; lanes
// 0-7 write 64B h sub-row. csr/r1 nt-loads, h nt-store protect the slice.
__global__ __launch_bounds__(256) void agg1_sliced(
        const int* __restrict__ rowstart, const int* __restrict__ csr,
        const unsigned* __restrict__ z1w, const float* __restrict__ r1,
        const float* __restrict__ b1, float* __restrict__ h) {
    const int role = blockIdx.x & 7;
    const int slice = role >> 1;                 // 0..3
    const int half = role & 1;                   // 0,1
    const int lane = threadIdx.x & 63;
    const int r = lane >> 3, f = lane & 7;
    const unsigned* zs = z1w + (size_t)slice * (N * 8);

    const int n0 = half * (N / 2);
    const int n1 = n0 + N / 2;
    const int wav = (blockIdx.x >> 3) * 4 + (threadIdx.x >> 6);
    const int nw = (gridDim.x >> 3) * 4;

    float2 bv;
    {
        unsigned long long bb = *(const unsigned long long*)(b1 + slice * 16 + 2 * f);
        bv = __builtin_bit_cast(float2, bb);
    }

    for (int n = n0 + wav; n < n1; n += nw) {
        const int beg = rowstart[n], end = rowstart[n + 1];
        float alo = 0.f, ahi = 0.f;
        for (int p = beg; p < end; p += 8) {
            int idx = p + r;
            if (idx < end) {
                int c = __builtin_nontemporal_load(&csr[idx]);
                unsigned u = zs[(size_t)c * 8 + f];
                alo += pk_lo(u);
                ahi += pk_hi(u);
            }
        }
        alo += __shfl_xor(alo, 8, 64);
        ahi += __shfl_xor(ahi, 8, 64);
        alo += __shfl_xor(alo, 16, 64);
        ahi += __shfl_xor(ahi, 16, 64);
        alo += __shfl_xor(alo, 32, 64);
        ahi += __shfl_xor(ahi, 32, 64);
        if (lane < 8) {
            float inv = (end > beg) ? 1.0f / (float)(end - beg) : 0.f;
            unsigned long long rr = __builtin_nontemporal_load(
                (const unsigned long long*)(r1 + (size_t)n * 64 + slice * 16 + 2 * f));
            float2 rv = __builtin_bit_cast(float2, rr);
            float2 o;
            o.x = fmaxf(alo * inv + bv.x + rv.x, 0.f);
            o.y = fmaxf(ahi * inv + bv.y + rv.y, 0.f);
            __builtin_nontemporal_store(__builtin_bit_cast(unsigned long long, o),
                (unsigned long long*)(h + (size_t)n * 64 + slice * 16 + 2 * f));
        }
    }
}

// ---------------- layer 2 aggregation (round-15 packed-dword version) ----------------
__global__ __launch_bounds__(256) void agg2_fused(
        const int* __restrict__ rowstart, const int* __restrict__ csr,
        const unsigned* __restrict__ z2w, const float* __restrict__ r2,
        const float* __restrict__ b2, float* __restrict__ out) {
    const int n = blockIdx.x * 4 + (threadIdx.x >> 6);
    if (n >= N) return;
    const int lane = threadIdx.x & 63;
    const int quad = lane >> 4;
    const int fl = lane & 15;
    const int beg = rowstart[n], end = rowstart[n + 1];
    float alo = 0.f, ahi = 0.f;
    int p = beg;
    for (; p + 8 <= end; p += 8) {
        int c0 = csr[p + quad], c1 = csr[p + 4 + quad];
        unsigned u0 = z2w[(size_t)c0 * 16 + fl];
        unsigned u1 = z2w[(size_t)c1 * 16 + fl];
        alo += pk_lo(u0) + pk_lo(u1);
        ahi += pk_hi(u0) + pk_hi(u1);
    }
    for (; p + 4 <= end; p += 4) {
        int c = csr[p + quad];
        unsigned u = z2w[(size_t)c * 16 + fl];
        alo += pk_lo(u);
        ahi += pk_hi(u);
    }
    if (p < end) {
        int rr = end - p;
        if (quad < rr) {
            int c = csr[p + quad];
            unsigned u = z2w[(size_t)c * 16 + fl];
            alo += pk_lo(u);
            ahi += pk_hi(u);
        }
    }
    alo += __shfl_xor(alo, 16, 64);
    ahi += __shfl_xor(ahi, 16, 64);
    alo += __shfl_xor(alo, 32, 64);
    ahi += __shfl_xor(ahi, 32, 64);
    if (lane < 16) {
        float inv = (end > beg) ? 1.0f / (float)(end - beg) : 0.f;
        float2 rv = ((const float2*)r2)[(size_t)n * 16 + fl];
        float2 bv = ((const float2*)b2)[fl];
        float2 o;
        o.x = alo * inv + bv.x + rv.x;
        o.y = ahi * inv + bv.y + rv.y;
        ((float2*)out)[(size_t)n * 16 + fl] = o;
    }
}

// ---------------- launch ----------------

extern "C" void kernel_launch(void* const* d_in, const int* in_sizes, int n_in,
                              void* d_out, int out_size, void* d_ws, size_t ws_size,
                              hipStream_t stream) {
    const float* x    = (const float*)d_in[0];
    const int*   raw  = (const int*)d_in[1];
    const float* W1l  = (const float*)d_in[2];
    const float* b1   = (const float*)d_in[3];
    const float* W1r  = (const float*)d_in[4];
    const float* W2l  = (const float*)d_in[5];
    const float* b2   = (const float*)d_in[6];
    const float* W2r  = (const float*)d_in[7];
    float* out = (float*)d_out;

    // byte-offset workspace layout
    char* wsb = (char*)d_ws;
    unsigned short* z1b = (unsigned short*)wsb;              // [4][N*16] bf16 slice-major (12.8MB)
    unsigned short* z2b = (unsigned short*)wsb;              // [N*32] overlays z1b
    float* r1 = (float*)(wsb + 16 * 1024 * 1024);            // [N*64] f32 (25.6MB)
    float* r2 = (float*)(wsb + 16 * 1024 * 1024);            // [N*32] overlays r1
    float* h  = (float*)(wsb + 48 * 1024 * 1024);            // [N*64] f32 (25.6MB)
    int2* bucket = (int2*)(wsb + 48 * 1024 * 1024);          // 64 x CAP x 8B (14.3MB)
    // bucket overlays h: buckets die (after fill2) before agg1 writes h.

    int* ibase    = (int*)(wsb + 80 * 1024 * 1024);
    int* counts   = ibase;                   // [N]
    int* rowstart = ibase + N;               // [N+1]
    int* bsum     = ibase + 2 * N + 1;       // [512]
    int* csr      = ibase + 2 * N + 1 + 512; // [E]
    int* flag     = csr + E;                 // [1]
    int* bcur     = flag + 1;                // [64]

    detect_dtype<<<1, 256, 0, stream>>>(raw, flag, bcur);
    bucket_edges<<<PA_BLOCKS, 256, 0, stream>>>(raw, flag, bcur, bucket);
    count2<<<NCHUNK, 1024, 0, stream>>>(bcur, bucket, counts);
    scan1<<<NBLK, 256, 0, stream>>>(counts, rowstart, bsum);
    scan2<<<1, 512, 0, stream>>>(bsum);
    scan3<<<NBLK, 256, 0, stream>>>(rowstart, bsum);
    fill2<<<NCHUNK, 1024, 0, stream>>>(bcur, bucket, rowstart, csr);

    transform1_mfma<<<1024, 256, 0, stream>>>(x, W1l, W1r, z1b, r1);
    agg1_sliced<<<2048, 256, 0, stream>>>(rowstart, csr, (const unsigned*)z1b, r1, b1, h);

    transform2_mfma<<<1024, 256, 0, stream>>>(h, W2l, W2r, z2b, r2);
    agg2_fused<<<(N + 3) / 4, 256, 0, stream>>>(rowstart, csr, (const unsigned*)z2b, r2, b2, out);
}

// Round 17
// 206.527 us; speedup vs baseline: 1.5473x; 1.5473x over previous
//
#include <hip/hip_runtime.h>

// GraphSAGE 2-layer, N=100000, E=1600000, 128 -> 64 -> 32.
// Round 17: REVERT round-16 slicing (157us vs 55: 4x csr re-read + 32B/line
// gathers + 1 outstanding load/wave — instruction efficiency beats cache
// residency when latency-bound). Forward on the proven axis instead:
//  - agg1: quarter-wave dwordx2 gathers (16 lanes x 8B = full 128B row per
//    instruction; 8 rows in flight at half round-15's instruction count)
//  - agg2: eighth-wave dwordx2 (8 lanes x 8B = 64B row; 8 rows/instruction)
//  - h stored bf16: numerically identical (transform2 rounded h to bf16
//    anyway) — kills 25.6MB of traffic + the cvt chain in transform2.
// CSR build + transforms otherwise byte-identical to round 15.

namespace {
constexpr int N = 100000;
constexpr int E = 1600000;
constexpr int NBLK = (N + 255) / 256;           // 391 scan blocks
constexpr int NT16 = N / 16;                    // 6250 node tiles (exact)
constexpr int NCHUNK = 64;                      // 1600 nodes per chunk
constexpr int CHUNK_N = 1600;
constexpr int CAP = 28000;                      // bucket capacity
constexpr int PA_BLOCKS = 256;
constexpr int PER_BLK = E / PA_BLOCKS;          // 6250 edges per block
}

using bf16x8 = __attribute__((ext_vector_type(8))) short;
using f32x4  = __attribute__((ext_vector_type(4))) float;

__device__ __forceinline__ unsigned short f2bf(float f) {
    unsigned u = __builtin_bit_cast(unsigned, f);
    u += 0x7FFFu + ((u >> 16) & 1u);            // RNE truncate to bf16
    return (unsigned short)(u >> 16);
}

__device__ __forceinline__ bf16x8 load_frag8(const float* __restrict__ p) {
    const float4* p4 = (const float4*)p;
    float4 f0 = p4[0], f1 = p4[1];
    bf16x8 r;
    r[0] = f2bf(f0.x); r[1] = f2bf(f0.y); r[2] = f2bf(f0.z); r[3] = f2bf(f0.w);
    r[4] = f2bf(f1.x); r[5] = f2bf(f1.y); r[6] = f2bf(f1.z); r[7] = f2bf(f1.w);
    return r;
}

// packed bf16 pair -> two floats
__device__ __forceinline__ float pk_lo(unsigned u) {
    return __builtin_bit_cast(float, u << 16);
}
__device__ __forceinline__ float pk_hi(unsigned u) {
    return __builtin_bit_cast(float, u & 0xFFFF0000u);
}
__device__ __forceinline__ unsigned pk2(float a, float b) {
    return (unsigned)f2bf(a) | ((unsigned)f2bf(b) << 16);
}

// ---------------- CSR build ----------------

__global__ __launch_bounds__(256) void detect_dtype(const int* __restrict__ raw,
                                                    int* __restrict__ flag,
                                                    int* __restrict__ bcur) {
    if (threadIdx.x < NCHUNK) bcur[threadIdx.x] = 0;
    int any = 0;
#pragma unroll
    for (int k = 0; k < 64; ++k) {
        int i = threadIdx.x + k * 256;          // first 16384 qwords
        any |= raw[2 * i + 1];
    }
    unsigned long long b = __ballot(any != 0);
    __shared__ int acc[4];
    int w = threadIdx.x >> 6;
    if ((threadIdx.x & 63) == 0) acc[w] = (b != 0ULL) ? 1 : 0;
    __syncthreads();
    if (threadIdx.x == 0) *flag = acc[0] | acc[1] | acc[2] | acc[3];
}

__global__ __launch_bounds__(256) void bucket_edges(
        const int* __restrict__ raw, const int* __restrict__ flag,
        int* __restrict__ bcur, int2* __restrict__ bucket) {
    __shared__ int cnt[NCHUNK];
    __shared__ int res[NCHUNK];
    if (threadIdx.x < NCHUNK) cnt[threadIdx.x] = 0;
    __syncthreads();
    const int is32 = *flag;
    const int e0 = blockIdx.x * PER_BLK;
    for (int i = threadIdx.x; i < PER_BLK; i += 256) {
        int e = e0 + i;
        int d = is32 ? raw[E + e] : raw[2 * ((long long)E + e)];
        atomicAdd(&cnt[d / CHUNK_N], 1);
    }
    __syncthreads();
    if (threadIdx.x < NCHUNK) {
        res[threadIdx.x] = atomicAdd(&bcur[threadIdx.x], cnt[threadIdx.x]);
        cnt[threadIdx.x] = 0;
    }
    __syncthreads();
    for (int i = threadIdx.x; i < PER_BLK; i += 256) {
        int e = e0 + i;
        int d, s;
        if (is32) { d = raw[E + e]; s = raw[e]; }
        else      { d = raw[2 * ((long long)E + e)]; s = raw[2 * (long long)e]; }
        int c = d / CHUNK_N;
        int pos = res[c] + atomicAdd(&cnt[c], 1);
        if (pos < CAP) bucket[(size_t)c * CAP + pos] = make_int2(s, d);
    }
}

__global__ __launch_bounds__(1024) void count2(
        const int* __restrict__ bcur, const int2* __restrict__ bucket,
        int* __restrict__ counts) {
    __shared__ int scnt[CHUNK_N];
    const int chunk = blockIdx.x;
    const int lo = chunk * CHUNK_N;
    for (int i = threadIdx.x; i < CHUNK_N; i += 1024) scnt[i] = 0;
    __syncthreads();
    int n = bcur[chunk]; if (n > CAP) n = CAP;
    const int2* b = bucket + (size_t)chunk * CAP;
    for (int i = threadIdx.x; i < n; i += 1024)
        atomicAdd(&scnt[b[i].y - lo], 1);
    __syncthreads();
    const int lim = N - lo;
    for (int i = threadIdx.x; i < CHUNK_N; i += 1024)
        if (i < lim) counts[lo + i] = scnt[i];
}

__global__ __launch_bounds__(256) void scan1(const int* __restrict__ counts,
                                             int* __restrict__ rowstart,
                                             int* __restrict__ bsum) {
    __shared__ int tmp[256];
    int t = threadIdx.x;
    int i = blockIdx.x * 256 + t;
    int v = (i < N) ? counts[i] : 0;
    tmp[t] = v;
    __syncthreads();
#pragma unroll
    for (int off = 1; off < 256; off <<= 1) {
        int a = (t >= off) ? tmp[t - off] : 0;
        __syncthreads();
        tmp[t] += a;
        __syncthreads();
    }
    if (i < N) rowstart[i] = tmp[t] - v;
    if (t == 255) bsum[blockIdx.x] = tmp[255];
}

__global__ __launch_bounds__(512) void scan2(int* __restrict__ bsum) {
    __shared__ int tmp[512];
    int t = threadIdx.x;
    int v = (t < NBLK) ? bsum[t] : 0;
    tmp[t] = v;
    __syncthreads();
#pragma unroll
    for (int off = 1; off < 512; off <<= 1) {
        int a = (t >= off) ? tmp[t - off] : 0;
        __syncthreads();
        tmp[t] += a;
        __syncthreads();
    }
    if (t < NBLK) bsum[t] = tmp[t] - v;
}

__global__ void scan3(int* __restrict__ rowstart, const int* __restrict__ bsum) {
    int i = blockIdx.x * blockDim.x + threadIdx.x;
    if (i < N) rowstart[i] += bsum[i >> 8];
    if (i == 0) rowstart[N] = E;
}

__global__ __launch_bounds__(1024) void fill2(
        const int* __restrict__ bcur, const int2* __restrict__ bucket,
        const int* __restrict__ rowstart, int* __restrict__ csr) {
    __shared__ int scur[CHUNK_N];
    const int chunk = blockIdx.x;
    const int lo = chunk * CHUNK_N;
    const int lim = N - lo;
    for (int i = threadIdx.x; i < CHUNK_N; i += 1024)
        scur[i] = (i < lim) ? rowstart[lo + i] : 0;
    __syncthreads();
    int n = bcur[chunk]; if (n > CAP) n = CAP;
    const int2* b = bucket + (size_t)chunk * CAP;
    for (int i = threadIdx.x; i < n; i += 1024) {
        int2 sd = b[i];
        int pos = atomicAdd(&scur[sd.y - lo], 1);
        csr[pos] = sd.x;
    }
}

// ---------------- layer 1 transform (MFMA): z1 node-major bf16, r1 f32 ----------------
__global__ __launch_bounds__(256) void transform1_mfma(
        const float* __restrict__ x, const float* __restrict__ W1l,
        const float* __restrict__ W1r, unsigned short* __restrict__ z1b,
        float* __restrict__ r1) {
    const int lane = threadIdx.x & 63;
    const int gw = blockIdx.x * 4 + (threadIdx.x >> 6);
    const int q = gw & 1;
    const int r16 = lane & 15;
    const int kgrp = lane >> 4;

    bf16x8 wf[2][2][4];
#pragma unroll
    for (int m = 0; m < 2; ++m) {
        const float* W = m ? W1r : W1l;
#pragma unroll
        for (int c = 0; c < 2; ++c) {
            const float* pw = W + (size_t)(q * 32 + c * 16 + r16) * 128 + kgrp * 8;
#pragma unroll
            for (int kb = 0; kb < 4; ++kb)
                wf[m][c][kb] = load_frag8(pw + kb * 32);
        }
    }

    const int stride = (gridDim.x * 4) >> 1;
    for (int t = gw >> 1; t < NT16; t += stride) {
        const float* px = x + ((size_t)t * 16 + r16) * 128 + kgrp * 8;
        bf16x8 af[4];
#pragma unroll
        for (int kb = 0; kb < 4; ++kb) af[kb] = load_frag8(px + kb * 32);

        f32x4 a00 = {0.f,0.f,0.f,0.f}, a01 = {0.f,0.f,0.f,0.f};
        f32x4 a10 = {0.f,0.f,0.f,0.f}, a11 = {0.f,0.f,0.f,0.f};
#pragma unroll
        for (int kb = 0; kb < 4; ++kb) {
            a00 = __builtin_amdgcn_mfma_f32_16x16x32_bf16(af[kb], wf[0][0][kb], a00, 0, 0, 0);
            a01 = __builtin_amdgcn_mfma_f32_16x16x32_bf16(af[kb], wf[0][1][kb], a01, 0, 0, 0);
            a10 = __builtin_amdgcn_mfma_f32_16x16x32_bf16(af[kb], wf[1][0][kb], a10, 0, 0, 0);
            a11 = __builtin_amdgcn_mfma_f32_16x16x32_bf16(af[kb], wf[1][1][kb], a11, 0, 0, 0);
        }
#pragma unroll
        for (int i = 0; i < 4; ++i) {
            size_t row = (size_t)t * 16 + kgrp * 4 + i;
            z1b[row * 64 + q * 32 +  0 + r16] = f2bf(a00[i]);
            z1b[row * 64 + q * 32 + 16 + r16] = f2bf(a01[i]);
            r1[row * 64 + q * 32 +  0 + r16] = a10[i];
            r1[row * 64 + q * 32 + 16 + r16] = a11[i];
        }
    }
}

// ---------------- layer 2 transform (MFMA): h is bf16 input ----------------
__global__ __launch_bounds__(256) void transform2_mfma(
        const unsigned short* __restrict__ hb, const float* __restrict__ W2l,
        const float* __restrict__ W2r, unsigned short* __restrict__ z2b,
        float* __restrict__ r2) {
    const int lane = threadIdx.x & 63;
    const int gw = blockIdx.x * 4 + (threadIdx.x >> 6);
    const int r16 = lane & 15;
    const int kgrp = lane >> 4;

    bf16x8 wf[2][2][2];
#pragma unroll
    for (int m = 0; m < 2; ++m) {
        const float* W = m ? W2r : W2l;
#pragma unroll
        for (int c = 0; c < 2; ++c) {
            const float* pw = W + (size_t)(c * 16 + r16) * 64 + kgrp * 8;
#pragma unroll
            for (int kb = 0; kb < 2; ++kb)
                wf[m][c][kb] = load_frag8(pw + kb * 32);
        }
    }

    for (int t = gw; t < NT16; t += gridDim.x * 4) {
        const unsigned short* ph = hb + ((size_t)t * 16 + r16) * 64 + kgrp * 8;
        bf16x8 af[2];
        af[0] = *(const bf16x8*)(ph);            // direct bf16 fragment (16B)
        af[1] = *(const bf16x8*)(ph + 32);

        f32x4 a00 = {0.f,0.f,0.f,0.f}, a01 = {0.f,0.f,0.f,0.f};
        f32x4 a10 = {0.f,0.f,0.f,0.f}, a11 = {0.f,0.f,0.f,0.f};
#pragma unroll
        for (int kb = 0; kb < 2; ++kb) {
            a00 = __builtin_amdgcn_mfma_f32_16x16x32_bf16(af[kb], wf[0][0][kb], a00, 0, 0, 0);
            a01 = __builtin_amdgcn_mfma_f32_16x16x32_bf16(af[kb], wf[0][1][kb], a01, 0, 0, 0);
            a10 = __builtin_amdgcn_mfma_f32_16x16x32_bf16(af[kb], wf[1][0][kb], a10, 0, 0, 0);
            a11 = __builtin_amdgcn_mfma_f32_16x16x32_bf16(af[kb], wf[1][1][kb], a11, 0, 0, 0);
        }
#pragma unroll
        for (int i = 0; i < 4; ++i) {
            size_t row = (size_t)t * 16 + kgrp * 4 + i;
            z2b[row * 32 +  0 + r16] = f2bf(a00[i]);
            z2b[row * 32 + 16 + r16] = f2bf(a01[i]);
            r2[row * 32 +  0 + r16] = a10[i];
            r2[row * 32 + 16 + r16] = a11[i];
        }
    }
}

// ---------------- layer 1 aggregation: quarter-wave dwordx2 gathers ----------------
// Wave per node. z1 row = 128B = 16 lanes x 8B. quad = row-in-batch (4 rows
// per gather instruction, x2 unrolled = 8 in flight). Lane fl holds feats
// 4fl..4fl+3. Folds: shfl_xor 16,32. Lanes 0-15 write h (bf16, uint2 = 4
// feats) -> 128B coalesced per node.
__global__ __launch_bounds__(256) void agg1_fused(
        const int* __restrict__ rowstart, const int* __restrict__ csr,
        const uint2* __restrict__ z1d, const float* __restrict__ r1,
        const float* __restrict__ b1, uint2* __restrict__ hb) {
    const int n = blockIdx.x * 4 + (threadIdx.x >> 6);
    if (n >= N) return;
    const int lane = threadIdx.x & 63;
    const int quad = lane >> 4;                  // 0..3
    const int fl = lane & 15;
    const int beg = rowstart[n], end = rowstart[n + 1];
    float a0 = 0.f, a1 = 0.f, a2 = 0.f, a3 = 0.f;
    int p = beg;
    for (; p + 8 <= end; p += 8) {
        int c0 = csr[p + quad], c1 = csr[p + 4 + quad];
        uint2 u0 = z1d[(size_t)c0 * 16 + fl];
        uint2 u1 = z1d[(size_t)c1 * 16 + fl];
        a0 += pk_lo(u0.x) + pk_lo(u1.x);
        a1 += pk_hi(u0.x) + pk_hi(u1.x);
        a2 += pk_lo(u0.y) + pk_lo(u1.y);
        a3 += pk_hi(u0.y) + pk_hi(u1.y);
    }
    for (; p + 4 <= end; p += 4) {
        int c = csr[p + quad];
        uint2 u = z1d[(size_t)c * 16 + fl];
        a0 += pk_lo(u.x); a1 += pk_hi(u.x);
        a2 += pk_lo(u.y); a3 += pk_hi(u.y);
    }
    if (p < end) {
        int rem = end - p;
        if (quad < rem) {
            int c = csr[p + quad];
            uint2 u = z1d[(size_t)c * 16 + fl];
            a0 += pk_lo(u.x); a1 += pk_hi(u.x);
            a2 += pk_lo(u.y); a3 += pk_hi(u.y);
        }
    }
    a0 += __shfl_xor(a0, 16, 64); a1 += __shfl_xor(a1, 16, 64);
    a2 += __shfl_xor(a2, 16, 64); a3 += __shfl_xor(a3, 16, 64);
    a0 += __shfl_xor(a0, 32, 64); a1 += __shfl_xor(a1, 32, 64);
    a2 += __shfl_xor(a2, 32, 64); a3 += __shfl_xor(a3, 32, 64);
    if (lane < 16) {
        float inv = (end > beg) ? 1.0f / (float)(end - beg) : 0.f;
        float4 rv = ((const float4*)r1)[(size_t)n * 16 + fl];
        float4 bv = ((const float4*)b1)[fl];
        float h0 = fmaxf(a0 * inv + bv.x + rv.x, 0.f);
        float h1 = fmaxf(a1 * inv + bv.y + rv.y, 0.f);
        float h2 = fmaxf(a2 * inv + bv.z + rv.z, 0.f);
        float h3 = fmaxf(a3 * inv + bv.w + rv.w, 0.f);
        uint2 o;
        o.x = pk2(h0, h1);
        o.y = pk2(h2, h3);
        hb[(size_t)n * 16 + fl] = o;
    }
}

// ---------------- layer 2 aggregation: eighth-wave dwordx2 gathers ----------------
// Wave per node. z2 row = 64B = 8 lanes x 8B. oct = row-in-batch (8 rows per
// gather instruction). Lane fl holds feats 4fl..4fl+3. Folds: shfl_xor
// 8,16,32. Lanes 0-7 write out (f32 float4 x ... 4 feats) -> 128B per node.
__global__ __launch_bounds__(256) void agg2_fused(
        const int* __restrict__ rowstart, const int* __restrict__ csr,
        const uint2* __restrict__ z2d, const float* __restrict__ r2,
        const float* __restrict__ b2, float* __restrict__ out) {
    const int n = blockIdx.x * 4 + (threadIdx.x >> 6);
    if (n >= N) return;
    const int lane = threadIdx.x & 63;
    const int oct = lane >> 3;                   // 0..7
    const int fl = lane & 7;
    const int beg = rowstart[n], end = rowstart[n + 1];
    float a0 = 0.f, a1 = 0.f, a2 = 0.f, a3 = 0.f;
    int p = beg;
    for (; p + 8 <= end; p += 8) {
        int c = csr[p + oct];
        uint2 u = z2d[(size_t)c * 8 + fl];
        a0 += pk_lo(u.x); a1 += pk_hi(u.x);
        a2 += pk_lo(u.y); a3 += pk_hi(u.y);
    }
    if (p < end) {
        int rem = end - p;
        if (oct < rem) {
            int c = csr[p + oct];
            uint2 u = z2d[(size_t)c * 8 + fl];
            a0 += pk_lo(u.x); a1 += pk_hi(u.x);
            a2 += pk_lo(u.y); a3 += pk_hi(u.y);
        }
    }
    a0 += __shfl_xor(a0, 8, 64);  a1 += __shfl_xor(a1, 8, 64);
    a2 += __shfl_xor(a2, 8, 64);  a3 += __shfl_xor(a3, 8, 64);
    a0 += __shfl_xor(a0, 16, 64); a1 += __shfl_xor(a1, 16, 64);
    a2 += __shfl_xor(a2, 16, 64); a3 += __shfl_xor(a3, 16, 64);
    a0 += __shfl_xor(a0, 32, 64); a1 += __shfl_xor(a1, 32, 64);
    a2 += __shfl_xor(a2, 32, 64); a3 += __shfl_xor(a3, 32, 64);
    if (lane < 8) {
        float inv = (end > beg) ? 1.0f / (float)(end - beg) : 0.f;
        float4 rv = ((const float4*)r2)[(size_t)n * 8 + fl];
        float4 bv = ((const float4*)b2)[fl];
        float4 o;
        o.x = a0 * inv + bv.x + rv.x;
        o.y = a1 * inv + bv.y + rv.y;
        o.z = a2 * inv + bv.z + rv.z;
        o.w = a3 * inv + bv.w + rv.w;
        ((float4*)out)[(size_t)n * 8 + fl] = o;
    }
}

// ---------------- launch ----------------

extern "C" void kernel_launch(void* const* d_in, const int* in_sizes, int n_in,
                              void* d_out, int out_size, void* d_ws, size_t ws_size,
                              hipStream_t stream) {
    const float* x    = (const float*)d_in[0];
    const int*   raw  = (const int*)d_in[1];
    const float* W1l  = (const float*)d_in[2];
    const float* b1   = (const float*)d_in[3];
    const float* W1r  = (const float*)d_in[4];
    const float* W2l  = (const float*)d_in[5];
    const float* b2   = (const float*)d_in[6];
    const float* W2r  = (const float*)d_in[7];
    float* out = (float*)d_out;

    // byte-offset workspace layout
    char* wsb = (char*)d_ws;
    unsigned short* z1b = (unsigned short*)wsb;              // [N*64] bf16 node-major (12.8MB)
    unsigned short* z2b = (unsigned short*)wsb;              // [N*32] overlays z1b
    float* r1 = (float*)(wsb + 16 * 1024 * 1024);            // [N*64] f32 (25.6MB)
    float* r2 = (float*)(wsb + 16 * 1024 * 1024);            // [N*32] overlays r1
    unsigned short* hb = (unsigned short*)(wsb + 48 * 1024 * 1024); // [N*64] bf16 (12.8MB)
    int2* bucket = (int2*)(wsb + 64 * 1024 * 1024);          // 64 x CAP x 8B (14.3MB)

    int* ibase    = (int*)(wsb + 80 * 1024 * 1024);
    int* counts   = ibase;                   // [N]
    int* rowstart = ibase + N;               // [N+1]
    int* bsum     = ibase + 2 * N + 1;       // [512]
    int* csr      = ibase + 2 * N + 1 + 512; // [E]
    int* flag     = csr + E;                 // [1]
    int* bcur     = flag + 1;                // [64]

    detect_dtype<<<1, 256, 0, stream>>>(raw, flag, bcur);
    bucket_edges<<<PA_BLOCKS, 256, 0, stream>>>(raw, flag, bcur, bucket);
    count2<<<NCHUNK, 1024, 0, stream>>>(bcur, bucket, counts);
    scan1<<<NBLK, 256, 0, stream>>>(counts, rowstart, bsum);
    scan2<<<1, 512, 0, stream>>>(bsum);
    scan3<<<NBLK, 256, 0, stream>>>(rowstart, bsum);
    fill2<<<NCHUNK, 1024, 0, stream>>>(bcur, bucket, rowstart, csr);

    transform1_mfma<<<1024, 256, 0, stream>>>(x, W1l, W1r, z1b, r1);
    agg1_fused<<<(N + 3) / 4, 256, 0, stream>>>(rowstart, csr, (const uint2*)z1b, r1, b1, (uint2*)hb);

    transform2_mfma<<<1024, 256, 0, stream>>>(hb, W2l, W2r, z2b, r2);
    agg2_fused<<<(N + 3) / 4, 256, 0, stream>>>(rowstart, csr, (const uint2*)z2b, r2, b2, out);
}

// Round 18
// 200.300 us; speedup vs baseline: 1.5954x; 1.0311x over previous
//
#include <hip/hip_runtime.h>

// GraphSAGE 2-layer, N=100000, E=1600000, 128 -> 64 -> 32.
// Round 18: consolidation. (1) count2+scan1+scan2+scan3+fill2 fused into ONE
// build_csr kernel (chunk base offsets = prefix of bcur, which bucket_edges
// already produced; local prefix via LDS scan) -> 12 dispatches become 7.
// (2) r1/r2 stored bf16 (h already was): -25MB traffic. (3) agg1 unroll 16.
// bucket_edges/detect/transform math/agg structure proven in rounds 14-17.

namespace {
constexpr int N = 100000;
constexpr int E = 1600000;
constexpr int NT16 = N / 16;                    // 6250 node tiles (exact)
constexpr int NCHUNK = 64;                      // 1600 nodes per chunk
constexpr int CHUNK_N = 1600;
constexpr int CAP = 28000;                      // bucket capacity (~19 sigma)
constexpr int PA_BLOCKS = 256;
constexpr int PER_BLK = E / PA_BLOCKS;          // 6250 edges per block
}

using bf16x8 = __attribute__((ext_vector_type(8))) short;
using f32x4  = __attribute__((ext_vector_type(4))) float;

__device__ __forceinline__ unsigned short f2bf(float f) {
    unsigned u = __builtin_bit_cast(unsigned, f);
    u += 0x7FFFu + ((u >> 16) & 1u);            // RNE truncate to bf16
    return (unsigned short)(u >> 16);
}

__device__ __forceinline__ bf16x8 load_frag8(const float* __restrict__ p) {
    const float4* p4 = (const float4*)p;
    float4 f0 = p4[0], f1 = p4[1];
    bf16x8 r;
    r[0] = f2bf(f0.x); r[1] = f2bf(f0.y); r[2] = f2bf(f0.z); r[3] = f2bf(f0.w);
    r[4] = f2bf(f1.x); r[5] = f2bf(f1.y); r[6] = f2bf(f1.z); r[7] = f2bf(f1.w);
    return r;
}

__device__ __forceinline__ float pk_lo(unsigned u) {
    return __builtin_bit_cast(float, u << 16);
}
__device__ __forceinline__ float pk_hi(unsigned u) {
    return __builtin_bit_cast(float, u & 0xFFFF0000u);
}
__device__ __forceinline__ unsigned pk2(float a, float b) {
    return (unsigned)f2bf(a) | ((unsigned)f2bf(b) << 16);
}

// ---------------- CSR build ----------------

// dtype detect (sample 16384 high words; int64 -> all zero) + zero bcur.
__global__ __launch_bounds__(256) void detect_dtype(const int* __restrict__ raw,
                                                    int* __restrict__ flag,
                                                    int* __restrict__ bcur) {
    if (threadIdx.x < NCHUNK) bcur[threadIdx.x] = 0;
    int any = 0;
#pragma unroll
    for (int k = 0; k < 64; ++k) {
        int i = threadIdx.x + k * 256;
        any |= raw[2 * i + 1];
    }
    unsigned long long b = __ballot(any != 0);
    __shared__ int acc[4];
    int w = threadIdx.x >> 6;
    if ((threadIdx.x & 63) == 0) acc[w] = (b != 0ULL) ? 1 : 0;
    __syncthreads();
    if (threadIdx.x == 0) *flag = acc[0] | acc[1] | acc[2] | acc[3];
}

__global__ __launch_bounds__(256) void bucket_edges(
        const int* __restrict__ raw, const int* __restrict__ flag,
        int* __restrict__ bcur, int2* __restrict__ bucket) {
    __shared__ int cnt[NCHUNK];
    __shared__ int res[NCHUNK];
    if (threadIdx.x < NCHUNK) cnt[threadIdx.x] = 0;
    __syncthreads();
    const int is32 = *flag;
    const int e0 = blockIdx.x * PER_BLK;
    for (int i = threadIdx.x; i < PER_BLK; i += 256) {
        int e = e0 + i;
        int d = is32 ? raw[E + e] : raw[2 * ((long long)E + e)];
        atomicAdd(&cnt[d / CHUNK_N], 1);
    }
    __syncthreads();
    if (threadIdx.x < NCHUNK) {
        res[threadIdx.x] = atomicAdd(&bcur[threadIdx.x], cnt[threadIdx.x]);
        cnt[threadIdx.x] = 0;
    }
    __syncthreads();
    for (int i = threadIdx.x; i < PER_BLK; i += 256) {
        int e = e0 + i;
        int d, s;
        if (is32) { d = raw[E + e]; s = raw[e]; }
        else      { d = raw[2 * ((long long)E + e)]; s = raw[2 * (long long)e]; }
        int c = d / CHUNK_N;
        int pos = res[c] + atomicAdd(&cnt[c], 1);
        if (pos < CAP) bucket[(size_t)c * CAP + pos] = make_int2(s, d);
    }
}

// Fused count + local scan + rowstart + fill. One block per chunk.
// base(chunk) = sum bcur[0..chunk); local exclusive prefix via LDS scan.
__global__ __launch_bounds__(1024) void build_csr(
        const int* __restrict__ bcur, const int2* __restrict__ bucket,
        int* __restrict__ rowstart, int* __restrict__ csr) {
    __shared__ int sc[2048];
    __shared__ int st[2048];
    __shared__ int sbase;
    const int chunk = blockIdx.x;
    const int lo = chunk * CHUNK_N;
    const int t = threadIdx.x;
    sc[t] = 0; sc[t + 1024] = 0;
    if (t == 0) {
        int bsum = 0;
        for (int c = 0; c < chunk; ++c) bsum += bcur[c];
        sbase = bsum;
    }
    __syncthreads();
    int n = bcur[chunk]; if (n > CAP) n = CAP;
    const int2* b = bucket + (size_t)chunk * CAP;
    for (int i = t; i < n; i += 1024)
        atomicAdd(&sc[b[i].y - lo], 1);
    __syncthreads();
    const int cA = sc[t], cB = sc[t + 1024];
    // inclusive Hillis-Steele over 2048, ping-pong sc<->st (11 steps)
    int* src = sc; int* dst = st;
    for (int off = 1; off < 2048; off <<= 1) {
        int vA = src[t] + ((t >= off) ? src[t - off] : 0);
        int vB = src[t + 1024] + src[t + 1024 - off];   // t+1024 >= off always (off<=1024)
        dst[t] = vA; dst[t + 1024] = vB;
        __syncthreads();
        int* tmp = src; src = dst; dst = tmp;
    }
    const int base = sbase;
    const int exA = base + src[t] - cA;
    const int exB = base + src[t + 1024] - cB;
    const int lim = N - lo;                       // may be <= 0 for the last chunk
    if (t < lim) rowstart[lo + t] = exA;
    if (t + 1024 < CHUNK_N && t + 1024 < lim) rowstart[lo + t + 1024] = exB;
    if (chunk == 0 && t == 0) rowstart[N] = E;
    // cursors in dst (the non-result buffer)
    dst[t] = exA; dst[t + 1024] = exB;
    __syncthreads();
    for (int i = t; i < n; i += 1024) {
        int2 sd = b[i];
        int pos = atomicAdd(&dst[sd.y - lo], 1);
        csr[pos] = sd.x;
    }
}

// ---------------- layer 1 transform (MFMA): z1 bf16, r1 bf16 ----------------
__global__ __launch_bounds__(256) void transform1_mfma(
        const float* __restrict__ x, const float* __restrict__ W1l,
        const float* __restrict__ W1r, unsigned short* __restrict__ z1b,
        unsigned short* __restrict__ r1b) {
    const int lane = threadIdx.x & 63;
    const int gw = blockIdx.x * 4 + (threadIdx.x >> 6);
    const int q = gw & 1;
    const int r16 = lane & 15;
    const int kgrp = lane >> 4;

    bf16x8 wf[2][2][4];
#pragma unroll
    for (int m = 0; m < 2; ++m) {
        const float* W = m ? W1r : W1l;
#pragma unroll
        for (int c = 0; c < 2; ++c) {
            const float* pw = W + (size_t)(q * 32 + c * 16 + r16) * 128 + kgrp * 8;
#pragma unroll
            for (int kb = 0; kb < 4; ++kb)
                wf[m][c][kb] = load_frag8(pw + kb * 32);
        }
    }

    const int stride = (gridDim.x * 4) >> 1;
    for (int t = gw >> 1; t < NT16; t += stride) {
        const float* px = x + ((size_t)t * 16 + r16) * 128 + kgrp * 8;
        bf16x8 af[4];
#pragma unroll
        for (int kb = 0; kb < 4; ++kb) af[kb] = load_frag8(px + kb * 32);

        f32x4 a00 = {0.f,0.f,0.f,0.f}, a01 = {0.f,0.f,0.f,0.f};
        f32x4 a10 = {0.f,0.f,0.f,0.f}, a11 = {0.f,0.f,0.f,0.f};
#pragma unroll
        for (int kb = 0; kb < 4; ++kb) {
            a00 = __builtin_amdgcn_mfma_f32_16x16x32_bf16(af[kb], wf[0][0][kb], a00, 0, 0, 0);
            a01 = __builtin_amdgcn_mfma_f32_16x16x32_bf16(af[kb], wf[0][1][kb], a01, 0, 0, 0);
            a10 = __builtin_amdgcn_mfma_f32_16x16x32_bf16(af[kb], wf[1][0][kb], a10, 0, 0, 0);
            a11 = __builtin_amdgcn_mfma_f32_16x16x32_bf16(af[kb], wf[1][1][kb], a11, 0, 0, 0);
        }
#pragma unroll
        for (int i = 0; i < 4; ++i) {
            size_t row = (size_t)t * 16 + kgrp * 4 + i;
            z1b[row * 64 + q * 32 +  0 + r16] = f2bf(a00[i]);
            z1b[row * 64 + q * 32 + 16 + r16] = f2bf(a01[i]);
            r1b[row * 64 + q * 32 +  0 + r16] = f2bf(a10[i]);
            r1b[row * 64 + q * 32 + 16 + r16] = f2bf(a11[i]);
        }
    }
}

// ---------------- layer 2 transform (MFMA): h bf16 in, z2/r2 bf16 out ----------------
__global__ __launch_bounds__(256) void transform2_mfma(
        const unsigned short* __restrict__ hb, const float* __restrict__ W2l,
        const float* __restrict__ W2r, unsigned short* __restrict__ z2b,
        unsigned short* __restrict__ r2b) {
    const int lane = threadIdx.x & 63;
    const int gw = blockIdx.x * 4 + (threadIdx.x >> 6);
    const int r16 = lane & 15;
    const int kgrp = lane >> 4;

    bf16x8 wf[2][2][2];
#pragma unroll
    for (int m = 0; m < 2; ++m) {
        const float* W = m ? W2r : W2l;
#pragma unroll
        for (int c = 0; c < 2; ++c) {
            const float* pw = W + (size_t)(c * 16 + r16) * 64 + kgrp * 8;
#pragma unroll
            for (int kb = 0; kb < 2; ++kb)
                wf[m][c][kb] = load_frag8(pw + kb * 32);
        }
    }

    for (int t = gw; t < NT16; t += gridDim.x * 4) {
        const unsigned short* ph = hb + ((size_t)t * 16 + r16) * 64 + kgrp * 8;
        bf16x8 af[2];
        af[0] = *(const bf16x8*)(ph);
        af[1] = *(const bf16x8*)(ph + 32);

        f32x4 a00 = {0.f,0.f,0.f,0.f}, a01 = {0.f,0.f,0.f,0.f};
        f32x4 a10 = {0.f,0.f,0.f,0.f}, a11 = {0.f,0.f,0.f,0.f};
#pragma unroll
        for (int kb = 0; kb < 2; ++kb) {
            a00 = __builtin_amdgcn_mfma_f32_16x16x32_bf16(af[kb], wf[0][0][kb], a00, 0, 0, 0);
            a01 = __builtin_amdgcn_mfma_f32_16x16x32_bf16(af[kb], wf[0][1][kb], a01, 0, 0, 0);
            a10 = __builtin_amdgcn_mfma_f32_16x16x32_bf16(af[kb], wf[1][0][kb], a10, 0, 0, 0);
            a11 = __builtin_amdgcn_mfma_f32_16x16x32_bf16(af[kb], wf[1][1][kb], a11, 0, 0, 0);
        }
#pragma unroll
        for (int i = 0; i < 4; ++i) {
            size_t row = (size_t)t * 16 + kgrp * 4 + i;
            z2b[row * 32 +  0 + r16] = f2bf(a00[i]);
            z2b[row * 32 + 16 + r16] = f2bf(a01[i]);
            r2b[row * 32 +  0 + r16] = f2bf(a10[i]);
            r2b[row * 32 + 16 + r16] = f2bf(a11[i]);
        }
    }
}

// ---------------- layer 1 aggregation: quarter-wave dwordx2, 16-row unroll ----------------
__global__ __launch_bounds__(256) void agg1_fused(
        const int* __restrict__ rowstart, const int* __restrict__ csr,
        const uint2* __restrict__ z1d, const uint2* __restrict__ r1d,
        const float* __restrict__ b1, uint2* __restrict__ hb) {
    const int n = blockIdx.x * 4 + (threadIdx.x >> 6);
    if (n >= N) return;
    const int lane = threadIdx.x & 63;
    const int quad = lane >> 4;
    const int fl = lane & 15;
    const int beg = rowstart[n], end = rowstart[n + 1];
    float a0 = 0.f, a1 = 0.f, a2 = 0.f, a3 = 0.f;
    int p = beg;
    for (; p + 16 <= end; p += 16) {
        int c0 = csr[p + quad],      c1 = csr[p + 4 + quad];
        int c2 = csr[p + 8 + quad],  c3 = csr[p + 12 + quad];
        uint2 u0 = z1d[(size_t)c0 * 16 + fl];
        uint2 u1 = z1d[(size_t)c1 * 16 + fl];
        uint2 u2 = z1d[(size_t)c2 * 16 + fl];
        uint2 u3 = z1d[(size_t)c3 * 16 + fl];
        a0 += pk_lo(u0.x) + pk_lo(u1.x) + pk_lo(u2.x) + pk_lo(u3.x);
        a1 += pk_hi(u0.x) + pk_hi(u1.x) + pk_hi(u2.x) + pk_hi(u3.x);
        a2 += pk_lo(u0.y) + pk_lo(u1.y) + pk_lo(u2.y) + pk_lo(u3.y);
        a3 += pk_hi(u0.y) + pk_hi(u1.y) + pk_hi(u2.y) + pk_hi(u3.y);
    }
    for (; p + 4 <= end; p += 4) {
        int c = csr[p + quad];
        uint2 u = z1d[(size_t)c * 16 + fl];
        a0 += pk_lo(u.x); a1 += pk_hi(u.x);
        a2 += pk_lo(u.y); a3 += pk_hi(u.y);
    }
    if (p < end) {
        int rem = end - p;
        if (quad < rem) {
            int c = csr[p + quad];
            uint2 u = z1d[(size_t)c * 16 + fl];
            a0 += pk_lo(u.x); a1 += pk_hi(u.x);
            a2 += pk_lo(u.y); a3 += pk_hi(u.y);
        }
    }
    a0 += __shfl_xor(a0, 16, 64); a1 += __shfl_xor(a1, 16, 64);
    a2 += __shfl_xor(a2, 16, 64); a3 += __shfl_xor(a3, 16, 64);
    a0 += __shfl_xor(a0, 32, 64); a1 += __shfl_xor(a1, 32, 64);
    a2 += __shfl_xor(a2, 32, 64); a3 += __shfl_xor(a3, 32, 64);
    if (lane < 16) {
        float inv = (end > beg) ? 1.0f / (float)(end - beg) : 0.f;
        uint2 rr = r1d[(size_t)n * 16 + fl];
        float4 bv = ((const float4*)b1)[fl];
        float h0 = fmaxf(a0 * inv + bv.x + pk_lo(rr.x), 0.f);
        float h1 = fmaxf(a1 * inv + bv.y + pk_hi(rr.x), 0.f);
        float h2 = fmaxf(a2 * inv + bv.z + pk_lo(rr.y), 0.f);
        float h3 = fmaxf(a3 * inv + bv.w + pk_hi(rr.y), 0.f);
        uint2 o;
        o.x = pk2(h0, h1);
        o.y = pk2(h2, h3);
        hb[(size_t)n * 16 + fl] = o;
    }
}

// ---------------- layer 2 aggregation: eighth-wave dwordx2 ----------------
__global__ __launch_bounds__(256) void agg2_fused(
        const int* __restrict__ rowstart, const int* __restrict__ csr,
        const uint2* __restrict__ z2d, const uint2* __restrict__ r2d,
        const float* __restrict__ b2, float* __restrict__ out) {
    const int n = blockIdx.x * 4 + (threadIdx.x >> 6);
    if (n >= N) return;
    const int lane = threadIdx.x & 63;
    const int oct = lane >> 3;
    const int fl = lane & 7;
    const int beg = rowstart[n], end = rowstart[n + 1];
    float a0 = 0.f, a1 = 0.f, a2 = 0.f, a3 = 0.f;
    int p = beg;
    for (; p + 8 <= end; p += 8) {
        int c = csr[p + oct];
        uint2 u = z2d[(size_t)c * 8 + fl];
        a0 += pk_lo(u.x); a1 += pk_hi(u.x);
        a2 += pk_lo(u.y); a3 += pk_hi(u.y);
    }
    if (p < end) {
        int rem = end - p;
        if (oct < rem) {
            int c = csr[p + oct];
            uint2 u = z2d[(size_t)c * 8 + fl];
            a0 += pk_lo(u.x); a1 += pk_hi(u.x);
            a2 += pk_lo(u.y); a3 += pk_hi(u.y);
        }
    }
    a0 += __shfl_xor(a0, 8, 64);  a1 += __shfl_xor(a1, 8, 64);
    a2 += __shfl_xor(a2, 8, 64);  a3 += __shfl_xor(a3, 8, 64);
    a0 += __shfl_xor(a0, 16, 64); a1 += __shfl_xor(a1, 16, 64);
    a2 += __shfl_xor(a2, 16, 64); a3 += __shfl_xor(a3, 16, 64);
    a0 += __shfl_xor(a0, 32, 64); a1 += __shfl_xor(a1, 32, 64);
    a2 += __shfl_xor(a2, 32, 64); a3 += __shfl_xor(a3, 32, 64);
    if (lane < 8) {
        float inv = (end > beg) ? 1.0f / (float)(end - beg) : 0.f;
        uint2 rr = r2d[(size_t)n * 8 + fl];
        float4 bv = ((const float4*)b2)[fl];
        float4 o;
        o.x = a0 * inv + bv.x + pk_lo(rr.x);
        o.y = a1 * inv + bv.y + pk_hi(rr.x);
        o.z = a2 * inv + bv.z + pk_lo(rr.y);
        o.w = a3 * inv + bv.w + pk_hi(rr.y);
        ((float4*)out)[(size_t)n * 8 + fl] = o;
    }
}

// ---------------- launch ----------------

extern "C" void kernel_launch(void* const* d_in, const int* in_sizes, int n_in,
                              void* d_out, int out_size, void* d_ws, size_t ws_size,
                              hipStream_t stream) {
    const float* x    = (const float*)d_in[0];
    const int*   raw  = (const int*)d_in[1];
    const float* W1l  = (const float*)d_in[2];
    const float* b1   = (const float*)d_in[3];
    const float* W1r  = (const float*)d_in[4];
    const float* W2l  = (const float*)d_in[5];
    const float* b2   = (const float*)d_in[6];
    const float* W2r  = (const float*)d_in[7];
    float* out = (float*)d_out;

    // byte-offset workspace layout
    char* wsb = (char*)d_ws;
    unsigned short* z1b = (unsigned short*)wsb;              // [N*64] bf16 (12.8MB)
    unsigned short* z2b = (unsigned short*)wsb;              // [N*32] overlays z1b
    unsigned short* r1b = (unsigned short*)(wsb + 16 * 1024 * 1024); // [N*64] bf16
    unsigned short* r2b = (unsigned short*)(wsb + 16 * 1024 * 1024); // [N*32] overlays r1b
    unsigned short* hb  = (unsigned short*)(wsb + 48 * 1024 * 1024); // [N*64] bf16
    int2* bucket = (int2*)(wsb + 64 * 1024 * 1024);          // 64 x CAP x 8B (14.3MB)

    int* ibase    = (int*)(wsb + 80 * 1024 * 1024);
    int* rowstart = ibase;                   // [N+1]
    int* csr      = ibase + N + 1;           // [E]
    int* flag     = csr + E;                 // [1]
    int* bcur     = flag + 1;                // [64]

    detect_dtype<<<1, 256, 0, stream>>>(raw, flag, bcur);
    bucket_edges<<<PA_BLOCKS, 256, 0, stream>>>(raw, flag, bcur, bucket);
    build_csr<<<NCHUNK, 1024, 0, stream>>>(bcur, bucket, rowstart, csr);

    transform1_mfma<<<1024, 256, 0, stream>>>(x, W1l, W1r, z1b, r1b);
    agg1_fused<<<(N + 3) / 4, 256, 0, stream>>>(rowstart, csr, (const uint2*)z1b,
                                                (const uint2*)r1b, b1, (uint2*)hb);

    transform2_mfma<<<1024, 256, 0, stream>>>(hb, W2l, W2r, z2b, r2b);
    agg2_fused<<<(N + 3) / 4, 256, 0, stream>>>(rowstart, csr, (const uint2*)z2b,
                                                (const uint2*)r2b, b2, out);
}

// Round 19
// 193.173 us; speedup vs baseline: 1.6543x; 1.0369x over previous
//
#include <hip/hip_runtime.h>

// GraphSAGE 2-layer, N=100000, E=1600000, 128 -> 64 -> 32.
// Round 19: (1) detect_dtype killed — each bucket block self-detects from 256
// high-words of its own edge range (P(misdetect)=1e-5^256=0); bcur zeroing is
// a 256B hipMemsetAsync. (2) transform1 co-scheduled with bucket_edges in one
// kernel via block-role branch (both 256-thr, independent data) — overlaps
// two ~20us memory-bound kernels. Round-18 evidence: agg1 pinned at 50us =
// L3 random-gather service floor (205MB logical / 4.1 TB/s); FETCH drop from
// bf16-r didn't move it -> stop optimizing agg1, cut the other 150us.
// build_csr / agg1 / transform2 / agg2 byte-identical to round 18.

namespace {
constexpr int N = 100000;
constexpr int E = 1600000;
constexpr int NT16 = N / 16;                    // 6250 node tiles (exact)
constexpr int NCHUNK = 64;                      // 1600 nodes per chunk
constexpr int CHUNK_N = 1600;
constexpr int CAP = 28000;                      // bucket capacity (~19 sigma)
constexpr int PA_BLOCKS = 256;
constexpr int PER_BLK = E / PA_BLOCKS;          // 6250 edges per block
constexpr int T1_BLOCKS = 1024;
}

using bf16x8 = __attribute__((ext_vector_type(8))) short;
using f32x4  = __attribute__((ext_vector_type(4))) float;

__device__ __forceinline__ unsigned short f2bf(float f) {
    unsigned u = __builtin_bit_cast(unsigned, f);
    u += 0x7FFFu + ((u >> 16) & 1u);            // RNE truncate to bf16
    return (unsigned short)(u >> 16);
}

__device__ __forceinline__ bf16x8 load_frag8(const float* __restrict__ p) {
    const float4* p4 = (const float4*)p;
    float4 f0 = p4[0], f1 = p4[1];
    bf16x8 r;
    r[0] = f2bf(f0.x); r[1] = f2bf(f0.y); r[2] = f2bf(f0.z); r[3] = f2bf(f0.w);
    r[4] = f2bf(f1.x); r[5] = f2bf(f1.y); r[6] = f2bf(f1.z); r[7] = f2bf(f1.w);
    return r;
}

__device__ __forceinline__ float pk_lo(unsigned u) {
    return __builtin_bit_cast(float, u << 16);
}
__device__ __forceinline__ float pk_hi(unsigned u) {
    return __builtin_bit_cast(float, u & 0xFFFF0000u);
}
__device__ __forceinline__ unsigned pk2(float a, float b) {
    return (unsigned)f2bf(a) | ((unsigned)f2bf(b) << 16);
}

// ---------------- fused bucket_edges + transform1 ----------------
// Blocks 0..255: partition edges into 64 dst-chunk buckets (self-detecting
// edge dtype). Blocks 256..1279: layer-1 MFMA transform. Independent data;
// whole blocks branch one way (no wave divergence).
__global__ __launch_bounds__(256) void bucket_t1(
        const int* __restrict__ raw, int* __restrict__ bcur,
        int2* __restrict__ bucket,
        const float* __restrict__ x, const float* __restrict__ W1l,
        const float* __restrict__ W1r, unsigned short* __restrict__ z1b,
        unsigned short* __restrict__ r1b) {
    __shared__ int cnt[NCHUNK];
    __shared__ int res[NCHUNK];
    __shared__ int sdet[4];

    if (blockIdx.x < PA_BLOCKS) {
        // ---- bucket role ----
        const int e0 = blockIdx.x * PER_BLK;
        // self-detect: 256 high words of this block's range; int64 -> all 0.
        int any = raw[2 * (e0 + threadIdx.x) + 1];
        unsigned long long bl = __ballot(any != 0);
        int w = threadIdx.x >> 6;
        if ((threadIdx.x & 63) == 0) sdet[w] = (bl != 0ULL) ? 1 : 0;
        if (threadIdx.x < NCHUNK) cnt[threadIdx.x] = 0;
        __syncthreads();
        const int is32 = sdet[0] | sdet[1] | sdet[2] | sdet[3];

        for (int i = threadIdx.x; i < PER_BLK; i += 256) {
            int e = e0 + i;
            int d = is32 ? raw[E + e] : raw[2 * ((long long)E + e)];
            atomicAdd(&cnt[d / CHUNK_N], 1);
        }
        __syncthreads();
        if (threadIdx.x < NCHUNK) {
            res[threadIdx.x] = atomicAdd(&bcur[threadIdx.x], cnt[threadIdx.x]);
            cnt[threadIdx.x] = 0;
        }
        __syncthreads();
        for (int i = threadIdx.x; i < PER_BLK; i += 256) {
            int e = e0 + i;
            int d, s;
            if (is32) { d = raw[E + e]; s = raw[e]; }
            else      { d = raw[2 * ((long long)E + e)]; s = raw[2 * (long long)e]; }
            int c = d / CHUNK_N;
            int pos = res[c] + atomicAdd(&cnt[c], 1);
            if (pos < CAP) bucket[(size_t)c * CAP + pos] = make_int2(s, d);
        }
        return;
    }

    // ---- transform1 role (identical math to round-18 transform1_mfma) ----
    const int bid = blockIdx.x - PA_BLOCKS;
    const int lane = threadIdx.x & 63;
    const int gw = bid * 4 + (threadIdx.x >> 6);
    const int q = gw & 1;
    const int r16 = lane & 15;
    const int kgrp = lane >> 4;

    bf16x8 wf[2][2][4];
#pragma unroll
    for (int m = 0; m < 2; ++m) {
        const float* W = m ? W1r : W1l;
#pragma unroll
        for (int c = 0; c < 2; ++c) {
            const float* pw = W + (size_t)(q * 32 + c * 16 + r16) * 128 + kgrp * 8;
#pragma unroll
            for (int kb = 0; kb < 4; ++kb)
                wf[m][c][kb] = load_frag8(pw + kb * 32);
        }
    }

    const int stride = (T1_BLOCKS * 4) >> 1;
    for (int t = gw >> 1; t < NT16; t += stride) {
        const float* px = x + ((size_t)t * 16 + r16) * 128 + kgrp * 8;
        bf16x8 af[4];
#pragma unroll
        for (int kb = 0; kb < 4; ++kb) af[kb] = load_frag8(px + kb * 32);

        f32x4 a00 = {0.f,0.f,0.f,0.f}, a01 = {0.f,0.f,0.f,0.f};
        f32x4 a10 = {0.f,0.f,0.f,0.f}, a11 = {0.f,0.f,0.f,0.f};
#pragma unroll
        for (int kb = 0; kb < 4; ++kb) {
            a00 = __builtin_amdgcn_mfma_f32_16x16x32_bf16(af[kb], wf[0][0][kb], a00, 0, 0, 0);
            a01 = __builtin_amdgcn_mfma_f32_16x16x32_bf16(af[kb], wf[0][1][kb], a01, 0, 0, 0);
            a10 = __builtin_amdgcn_mfma_f32_16x16x32_bf16(af[kb], wf[1][0][kb], a10, 0, 0, 0);
            a11 = __builtin_amdgcn_mfma_f32_16x16x32_bf16(af[kb], wf[1][1][kb], a11, 0, 0, 0);
        }
#pragma unroll
        for (int i = 0; i < 4; ++i) {
            size_t row = (size_t)t * 16 + kgrp * 4 + i;
            z1b[row * 64 + q * 32 +  0 + r16] = f2bf(a00[i]);
            z1b[row * 64 + q * 32 + 16 + r16] = f2bf(a01[i]);
            r1b[row * 64 + q * 32 +  0 + r16] = f2bf(a10[i]);
            r1b[row * 64 + q * 32 + 16 + r16] = f2bf(a11[i]);
        }
    }
}

// ---------------- build_csr (round-18, unchanged) ----------------
__global__ __launch_bounds__(1024) void build_csr(
        const int* __restrict__ bcur, const int2* __restrict__ bucket,
        int* __restrict__ rowstart, int* __restrict__ csr) {
    __shared__ int sc[2048];
    __shared__ int st[2048];
    __shared__ int sbase;
    const int chunk = blockIdx.x;
    const int lo = chunk * CHUNK_N;
    const int t = threadIdx.x;
    sc[t] = 0; sc[t + 1024] = 0;
    if (t == 0) {
        int bsum = 0;
        for (int c = 0; c < chunk; ++c) bsum += bcur[c];
        sbase = bsum;
    }
    __syncthreads();
    int n = bcur[chunk]; if (n > CAP) n = CAP;
    const int2* b = bucket + (size_t)chunk * CAP;
    for (int i = t; i < n; i += 1024)
        atomicAdd(&sc[b[i].y - lo], 1);
    __syncthreads();
    const int cA = sc[t], cB = sc[t + 1024];
    int* src = sc; int* dst = st;
    for (int off = 1; off < 2048; off <<= 1) {
        int vA = src[t] + ((t >= off) ? src[t - off] : 0);
        int vB = src[t + 1024] + src[t + 1024 - off];
        dst[t] = vA; dst[t + 1024] = vB;
        __syncthreads();
        int* tmp = src; src = dst; dst = tmp;
    }
    const int base = sbase;
    const int exA = base + src[t] - cA;
    const int exB = base + src[t + 1024] - cB;
    const int lim = N - lo;
    if (t < lim) rowstart[lo + t] = exA;
    if (t + 1024 < CHUNK_N && t + 1024 < lim) rowstart[lo + t + 1024] = exB;
    if (chunk == 0 && t == 0) rowstart[N] = E;
    dst[t] = exA; dst[t + 1024] = exB;
    __syncthreads();
    for (int i = t; i < n; i += 1024) {
        int2 sd = b[i];
        int pos = atomicAdd(&dst[sd.y - lo], 1);
        csr[pos] = sd.x;
    }
}

// ---------------- layer 2 transform (round-18, unchanged) ----------------
__global__ __launch_bounds__(256) void transform2_mfma(
        const unsigned short* __restrict__ hb, const float* __restrict__ W2l,
        const float* __restrict__ W2r, unsigned short* __restrict__ z2b,
        unsigned short* __restrict__ r2b) {
    const int lane = threadIdx.x & 63;
    const int gw = blockIdx.x * 4 + (threadIdx.x >> 6);
    const int r16 = lane & 15;
    const int kgrp = lane >> 4;

    bf16x8 wf[2][2][2];
#pragma unroll
    for (int m = 0; m < 2; ++m) {
        const float* W = m ? W2r : W2l;
#pragma unroll
        for (int c = 0; c < 2; ++c) {
            const float* pw = W + (size_t)(c * 16 + r16) * 64 + kgrp * 8;
#pragma unroll
            for (int kb = 0; kb < 2; ++kb)
                wf[m][c][kb] = load_frag8(pw + kb * 32);
        }
    }

    for (int t = gw; t < NT16; t += gridDim.x * 4) {
        const unsigned short* ph = hb + ((size_t)t * 16 + r16) * 64 + kgrp * 8;
        bf16x8 af[2];
        af[0] = *(const bf16x8*)(ph);
        af[1] = *(const bf16x8*)(ph + 32);

        f32x4 a00 = {0.f,0.f,0.f,0.f}, a01 = {0.f,0.f,0.f,0.f};
        f32x4 a10 = {0.f,0.f,0.f,0.f}, a11 = {0.f,0.f,0.f,0.f};
#pragma unroll
        for (int kb = 0; kb < 2; ++kb) {
            a00 = __builtin_amdgcn_mfma_f32_16x16x32_bf16(af[kb], wf[0][0][kb], a00, 0, 0, 0);
            a01 = __builtin_amdgcn_mfma_f32_16x16x32_bf16(af[kb], wf[0][1][kb], a01, 0, 0, 0);
            a10 = __builtin_amdgcn_mfma_f32_16x16x32_bf16(af[kb], wf[1][0][kb], a10, 0, 0, 0);
            a11 = __builtin_amdgcn_mfma_f32_16x16x32_bf16(af[kb], wf[1][1][kb], a11, 0, 0, 0);
        }
#pragma unroll
        for (int i = 0; i < 4; ++i) {
            size_t row = (size_t)t * 16 + kgrp * 4 + i;
            z2b[row * 32 +  0 + r16] = f2bf(a00[i]);
            z2b[row * 32 + 16 + r16] = f2bf(a01[i]);
            r2b[row * 32 +  0 + r16] = f2bf(a10[i]);
            r2b[row * 32 + 16 + r16] = f2bf(a11[i]);
        }
    }
}

// ---------------- layer 1 aggregation (round-18, unchanged) ----------------
__global__ __launch_bounds__(256) void agg1_fused(
        const int* __restrict__ rowstart, const int* __restrict__ csr,
        const uint2* __restrict__ z1d, const uint2* __restrict__ r1d,
        const float* __restrict__ b1, uint2* __restrict__ hb) {
    const int n = blockIdx.x * 4 + (threadIdx.x >> 6);
    if (n >= N) return;
    const int lane = threadIdx.x & 63;
    const int quad = lane >> 4;
    const int fl = lane & 15;
    const int beg = rowstart[n], end = rowstart[n + 1];
    float a0 = 0.f, a1 = 0.f, a2 = 0.f, a3 = 0.f;
    int p = beg;
    for (; p + 16 <= end; p += 16) {
        int c0 = csr[p + quad],      c1 = csr[p + 4 + quad];
        int c2 = csr[p + 8 + quad],  c3 = csr[p + 12 + quad];
        uint2 u0 = z1d[(size_t)c0 * 16 + fl];
        uint2 u1 = z1d[(size_t)c1 * 16 + fl];
        uint2 u2 = z1d[(size_t)c2 * 16 + fl];
        uint2 u3 = z1d[(size_t)c3 * 16 + fl];
        a0 += pk_lo(u0.x) + pk_lo(u1.x) + pk_lo(u2.x) + pk_lo(u3.x);
        a1 += pk_hi(u0.x) + pk_hi(u1.x) + pk_hi(u2.x) + pk_hi(u3.x);
        a2 += pk_lo(u0.y) + pk_lo(u1.y) + pk_lo(u2.y) + pk_lo(u3.y);
        a3 += pk_hi(u0.y) + pk_hi(u1.y) + pk_hi(u2.y) + pk_hi(u3.y);
    }
    for (; p + 4 <= end; p += 4) {
        int c = csr[p + quad];
        uint2 u = z1d[(size_t)c * 16 + fl];
        a0 += pk_lo(u.x); a1 += pk_hi(u.x);
        a2 += pk_lo(u.y); a3 += pk_hi(u.y);
    }
    if (p < end) {
        int rem = end - p;
        if (quad < rem) {
            int c = csr[p + quad];
            uint2 u = z1d[(size_t)c * 16 + fl];
            a0 += pk_lo(u.x); a1 += pk_hi(u.x);
            a2 += pk_lo(u.y); a3 += pk_hi(u.y);
        }
    }
    a0 += __shfl_xor(a0, 16, 64); a1 += __shfl_xor(a1, 16, 64);
    a2 += __shfl_xor(a2, 16, 64); a3 += __shfl_xor(a3, 16, 64);
    a0 += __shfl_xor(a0, 32, 64); a1 += __shfl_xor(a1, 32, 64);
    a2 += __shfl_xor(a2, 32, 64); a3 += __shfl_xor(a3, 32, 64);
    if (lane < 16) {
        float inv = (end > beg) ? 1.0f / (float)(end - beg) : 0.f;
        uint2 rr = r1d[(size_t)n * 16 + fl];
        float4 bv = ((const float4*)b1)[fl];
        float h0 = fmaxf(a0 * inv + bv.x + pk_lo(rr.x), 0.f);
        float h1 = fmaxf(a1 * inv + bv.y + pk_hi(rr.x), 0.f);
        float h2 = fmaxf(a2 * inv + bv.z + pk_lo(rr.y), 0.f);
        float h3 = fmaxf(a3 * inv + bv.w + pk_hi(rr.y), 0.f);
        uint2 o;
        o.x = pk2(h0, h1);
        o.y = pk2(h2, h3);
        hb[(size_t)n * 16 + fl] = o;
    }
}

// ---------------- layer 2 aggregation (round-18, unchanged) ----------------
__global__ __launch_bounds__(256) void agg2_fused(
        const int* __restrict__ rowstart, const int* __restrict__ csr,
        const uint2* __restrict__ z2d, const uint2* __restrict__ r2d,
        const float* __restrict__ b2, float* __restrict__ out) {
    const int n = blockIdx.x * 4 + (threadIdx.x >> 6);
    if (n >= N) return;
    const int lane = threadIdx.x & 63;
    const int oct = lane >> 3;
    const int fl = lane & 7;
    const int beg = rowstart[n], end = rowstart[n + 1];
    float a0 = 0.f, a1 = 0.f, a2 = 0.f, a3 = 0.f;
    int p = beg;
    for (; p + 8 <= end; p += 8) {
        int c = csr[p + oct];
        uint2 u = z2d[(size_t)c * 8 + fl];
        a0 += pk_lo(u.x); a1 += pk_hi(u.x);
        a2 += pk_lo(u.y); a3 += pk_hi(u.y);
    }
    if (p < end) {
        int rem = end - p;
        if (oct < rem) {
            int c = csr[p + oct];
            uint2 u = z2d[(size_t)c * 8 + fl];
            a0 += pk_lo(u.x); a1 += pk_hi(u.x);
            a2 += pk_lo(u.y); a3 += pk_hi(u.y);
        }
    }
    a0 += __shfl_xor(a0, 8, 64);  a1 += __shfl_xor(a1, 8, 64);
    a2 += __shfl_xor(a2, 8, 64);  a3 += __shfl_xor(a3, 8, 64);
    a0 += __shfl_xor(a0, 16, 64); a1 += __shfl_xor(a1, 16, 64);
    a2 += __shfl_xor(a2, 16, 64); a3 += __shfl_xor(a3, 16, 64);
    a0 += __shfl_xor(a0, 32, 64); a1 += __shfl_xor(a1, 32, 64);
    a2 += __shfl_xor(a2, 32, 64); a3 += __shfl_xor(a3, 32, 64);
    if (lane < 8) {
        float inv = (end > beg) ? 1.0f / (float)(end - beg) : 0.f;
        uint2 rr = r2d[(size_t)n * 8 + fl];
        float4 bv = ((const float4*)b2)[fl];
        float4 o;
        o.x = a0 * inv + bv.x + pk_lo(rr.x);
        o.y = a1 * inv + bv.y + pk_hi(rr.x);
        o.z = a2 * inv + bv.z + pk_lo(rr.y);
        o.w = a3 * inv + bv.w + pk_hi(rr.y);
        ((float4*)out)[(size_t)n * 8 + fl] = o;
    }
}

// ---------------- launch ----------------

extern "C" void kernel_launch(void* const* d_in, const int* in_sizes, int n_in,
                              void* d_out, int out_size, void* d_ws, size_t ws_size,
                              hipStream_t stream) {
    const float* x    = (const float*)d_in[0];
    const int*   raw  = (const int*)d_in[1];
    const float* W1l  = (const float*)d_in[2];
    const float* b1   = (const float*)d_in[3];
    const float* W1r  = (const float*)d_in[4];
    const float* W2l  = (const float*)d_in[5];
    const float* b2   = (const float*)d_in[6];
    const float* W2r  = (const float*)d_in[7];
    float* out = (float*)d_out;

    // byte-offset workspace layout
    char* wsb = (char*)d_ws;
    unsigned short* z1b = (unsigned short*)wsb;              // [N*64] bf16 (12.8MB)
    unsigned short* z2b = (unsigned short*)wsb;              // [N*32] overlays z1b
    unsigned short* r1b = (unsigned short*)(wsb + 16 * 1024 * 1024); // [N*64] bf16
    unsigned short* r2b = (unsigned short*)(wsb + 16 * 1024 * 1024); // [N*32] overlays r1b
    unsigned short* hb  = (unsigned short*)(wsb + 48 * 1024 * 1024); // [N*64] bf16
    int2* bucket = (int2*)(wsb + 64 * 1024 * 1024);          // 64 x CAP x 8B (14.3MB)

    int* ibase    = (int*)(wsb + 80 * 1024 * 1024);
    int* rowstart = ibase;                   // [N+1]
    int* csr      = ibase + N + 1;           // [E]
    int* bcur     = csr + E;                 // [64]

    hipMemsetAsync(bcur, 0, NCHUNK * sizeof(int), stream);
    bucket_t1<<<PA_BLOCKS + T1_BLOCKS, 256, 0, stream>>>(
        raw, bcur, bucket, x, W1l, W1r, z1b, r1b);
    build_csr<<<NCHUNK, 1024, 0, stream>>>(bcur, bucket, rowstart, csr);

    agg1_fused<<<(N + 3) / 4, 256, 0, stream>>>(rowstart, csr, (const uint2*)z1b,
                                                (const uint2*)r1b, b1, (uint2*)hb);

    transform2_mfma<<<1024, 256, 0, stream>>>(hb, W2l, W2r, z2b, r2b);
    agg2_fused<<<(N + 3) / 4, 256, 0, stream>>>(rowstart, csr, (const uint2*)z2b,
                                                (const uint2*)r2b, b2, out);
}